// Round 7
// baseline (403.570 us; speedup 1.0000x reference)
//
#include <hip/hip_runtime.h>
#include <cstdint>
#include <cstddef>

// ---------------------------------------------------------------------------
// BNN classifier: 3x binarized conv+BN+sign, avgpool, FC.
// Exact integer XNOR-popcount; interior pixels use exact precomputed integer
// thresholds (binary-scan of the monotone fp32 BN curve, same __f*_rn ops).
// R7: layer1 4px/thread; threshold epilogues; fc merged into layer3.
// ---------------------------------------------------------------------------

__device__ __align__(16) uint32_t g_h1p[32 * 224 * 224];
__device__ __align__(16) uint32_t g_h2lo[32 * 112 * 112];
__device__ __align__(16) uint32_t g_h2hi[32 * 112 * 112];
__device__ uint32_t g_w1p[32];
__device__ uint32_t g_w2p[576];
__device__ uint64_t g_w3p[1152];
__device__ float    g_inv1[32],  g_sh1[32];
__device__ float    g_inv2[64],  g_sh2[64];
__device__ float    g_inv3[128], g_sh3[128];
__device__ int      g_thr1[32];    // interior mismatch thresholds (nvalid=27)
__device__ uint32_t g_pol1;
__device__ int      g_thr2[64];    // interior thresholds (base=288)
__device__ uint32_t g_pol2[2];
__device__ int      g_acc[32 * 128];
__device__ int      g_done;

__device__ __forceinline__ int bn_neg(int s, float inv, float sh) {
    float y = __fadd_rn(__fmul_rn((float)s, inv), sh);
    return (y < 0.0f) ? 1 : 0;
}

// ---------- prep ------------------------------------------------------------
__global__ void prep_kernel(
    const float* __restrict__ w1, const float* __restrict__ w2, const float* __restrict__ w3,
    const float* __restrict__ g1, const float* __restrict__ b1, const float* __restrict__ m1, const float* __restrict__ v1,
    const float* __restrict__ g2, const float* __restrict__ b2, const float* __restrict__ m2, const float* __restrict__ v2,
    const float* __restrict__ g3, const float* __restrict__ b3, const float* __restrict__ m3, const float* __restrict__ v3)
{
    int tid = blockIdx.x * blockDim.x + threadIdx.x;
    int lt  = threadIdx.x;

    if (tid < 32 * 128) g_acc[tid] = 0;
    if (tid == 0) g_done = 0;

    // ---- weight packing (any block) ----
    if (tid < 32) {
        uint32_t m = 0;
        for (int t = 0; t < 27; ++t)
            m |= (w1[tid * 27 + t] < 0.0f ? 1u : 0u) << t;
        g_w1p[tid] = m;
    }
    if (tid < 576) {
        int oc = tid / 9, tap = tid % 9, ky = tap / 3, kx = tap % 3;
        uint32_t m = 0;
        for (int ic = 0; ic < 32; ++ic)
            m |= (w2[((oc * 32 + ic) * 3 + ky) * 3 + kx] < 0.0f ? 1u : 0u) << ic;
        g_w2p[tid] = m;
    }
    if (tid < 1152) {
        int oc = tid / 9, tap = tid % 9, ky = tap / 3, kx = tap % 3;
        uint64_t m = 0;
        for (int ic = 0; ic < 64; ++ic)
            m |= (uint64_t)(w3[((oc * 64 + ic) * 3 + ky) * 3 + kx] < 0.0f ? 1u : 0u) << ic;
        g_w3p[tid] = m;
    }

    // ---- BN tables + thresholds: block 0 only (needs intra-block sync) ----
    if (blockIdx.x == 0) {
        if (lt < 32) {
            float inv = __fdiv_rn(g1[lt], __fsqrt_rn(__fadd_rn(v1[lt], 1e-5f)));
            g_inv1[lt] = inv;
            g_sh1[lt] = __fsub_rn(b1[lt], __fmul_rn(m1[lt], inv));
        } else if (lt < 96) {
            int c = lt - 32;
            float inv = __fdiv_rn(g2[c], __fsqrt_rn(__fadd_rn(v2[c], 1e-5f)));
            g_inv2[c] = inv;
            g_sh2[c] = __fsub_rn(b2[c], __fmul_rn(m2[c], inv));
        } else if (lt < 224) {
            int c = lt - 96;
            float inv = __fdiv_rn(g3[c], __fsqrt_rn(__fadd_rn(v3[c], 1e-5f)));
            g_inv3[c] = inv;
            g_sh3[c] = __fsub_rn(b3[c], __fmul_rn(m3[c], inv));
        }
        __syncthreads();

        __shared__ uint32_t p1bits[32];
        __shared__ uint32_t p2bits[64];
        if (lt < 32) {  // layer1 interior: s = 27 - 2m, m in 0..27
            float inv = g_inv1[lt], sh = g_sh1[lt];
            int P = bn_neg(27 - 2 * 27, inv, sh);
            int M = 28;
            for (int m = 0; m <= 27; ++m)
                if (bn_neg(27 - 2 * m, inv, sh) == P) { M = m; break; }
            g_thr1[lt] = M;
            p1bits[lt] = (uint32_t)P;
        }
        if (lt >= 64 && lt < 128) {  // layer2 interior: s = 288 - 2m
            int c = lt - 64;
            float inv = g_inv2[c], sh = g_sh2[c];
            int P = bn_neg(288 - 2 * 288, inv, sh);
            int M = 289;
            for (int m = 0; m <= 288; ++m)
                if (bn_neg(288 - 2 * m, inv, sh) == P) { M = m; break; }
            g_thr2[c] = M;
            p2bits[c] = (uint32_t)P;
        }
        __syncthreads();
        if (lt == 0) {
            uint32_t p = 0;
            for (int i = 0; i < 32; ++i) p |= p1bits[i] << i;
            g_pol1 = p;
            uint32_t plo = 0, phi = 0;
            for (int i = 0; i < 32; ++i) { plo |= p2bits[i] << i; phi |= p2bits[32 + i] << i; }
            g_pol2[0] = plo; g_pol2[1] = phi;
        }
    }
}

// ---------- layer 1: 4 pixels/thread ---------------------------------------
__global__ void layer1_kernel(const float* __restrict__ x)
{
    int idx = blockIdx.x * blockDim.x + threadIdx.x;
    const int total = 32 * 224 * 56;
    if (idx >= total) return;
    int xq = idx % 56;
    int t  = idx / 56;
    int yy = t % 224;
    int b  = t / 224;
    int xx0 = xq * 4;

    const float* xb = x + (size_t)b * 3 * 224 * 224;
    uint32_t outw[4];

    bool interior = (yy >= 1) && (yy <= 222) && (xq >= 1) && (xq <= 54);
    if (interior) {
        // 6 column-sign bits per (channel,row), shared by the 4 pixels
        uint32_t cb[3][3];
#pragma unroll
        for (int ic = 0; ic < 3; ++ic)
#pragma unroll
        for (int r = 0; r < 3; ++r) {
            const float* p = xb + ((size_t)ic * 224 + (yy - 1 + r)) * 224 + (xx0 - 1);
            uint32_t bits = 0;
#pragma unroll
            for (int j = 0; j < 6; ++j)
                bits |= (p[j] < 0.0f ? 1u : 0u) << j;
            cb[ic][r] = bits;
        }
        uint32_t xm[4];
#pragma unroll
        for (int p = 0; p < 4; ++p) {
            uint32_t m = 0;
#pragma unroll
            for (int ic = 0; ic < 3; ++ic)
#pragma unroll
            for (int r = 0; r < 3; ++r)
                m |= ((cb[ic][r] >> p) & 7u) << (ic * 9 + r * 3);
            xm[p] = m;
        }
#pragma unroll
        for (int p = 0; p < 4; ++p) outw[p] = 0;
#pragma unroll
        for (int oc = 0; oc < 32; ++oc) {
            uint32_t w = g_w1p[oc];          // uniform -> scalar
            int M = g_thr1[oc];
#pragma unroll
            for (int p = 0; p < 4; ++p) {
                int mm = __popc(xm[p] ^ w);
                outw[p] |= (mm < M ? 1u : 0u) << oc;
            }
        }
        uint32_t pol = g_pol1;
#pragma unroll
        for (int p = 0; p < 4; ++p) outw[p] ^= pol;
    } else {
        // border quad: exact per-pixel float path (R5 math)
#pragma unroll
        for (int p = 0; p < 4; ++p) {
            int xx = xx0 + p;
            uint32_t xmask = 0, vmask = 0;
#pragma unroll
            for (int ky = 0; ky < 3; ++ky) {
                int iy = yy - 1 + ky;
                bool vy = (iy >= 0 && iy < 224);
#pragma unroll
                for (int kx = 0; kx < 3; ++kx) {
                    int ix = xx - 1 + kx;
                    bool v = vy && (ix >= 0) && (ix < 224);
                    if (v) {
                        int sp = ky * 3 + kx;
#pragma unroll
                        for (int ic = 0; ic < 3; ++ic) {
                            float val = xb[((size_t)ic * 224 + iy) * 224 + ix];
                            xmask |= (val < 0.0f ? 1u : 0u) << (ic * 9 + sp);
                            vmask |= 1u << (ic * 9 + sp);
                        }
                    }
                }
            }
            int nvalid = __popc(vmask);
            uint32_t ow = 0;
#pragma unroll
            for (int oc = 0; oc < 32; ++oc) {
                int mism = __popc((xmask ^ g_w1p[oc]) & vmask);
                int s = nvalid - 2 * mism;
                float y = __fadd_rn(__fmul_rn((float)s, g_inv1[oc]), g_sh1[oc]);
                ow |= (y < 0.0f ? 1u : 0u) << oc;
            }
            outw[p] = ow;
        }
    }
    uint4 o = make_uint4(outw[0], outw[1], outw[2], outw[3]);
    *(uint4*)&g_h1p[((size_t)b * 224 + yy) * 224 + xx0] = o;
}

// ---------- layer 2 ---------------------------------------------------------
__global__ void layer2_kernel()
{
    int half = blockIdx.y;
    int idx = blockIdx.x * blockDim.x + threadIdx.x;
    const int total = 32 * 112 * 112;
    if (idx >= total) return;
    int ox = idx % 112;
    int t = idx / 112;
    int oy = t % 112;
    int b = t / 112;

    const uint32_t* hb = g_h1p + (size_t)b * 224 * 224;
    const uint32_t* wp = g_w2p + half * 288;
    uint32_t outw = 0;

    if (ox >= 1 && oy >= 1) {
        uint32_t hw[9];
#pragma unroll
        for (int ky = 0; ky < 3; ++ky) {
            const uint32_t* row = hb + (2 * oy - 1 + ky) * 224 + (2 * ox - 1);
            hw[ky * 3 + 0] = row[0];
            hw[ky * 3 + 1] = row[1];
            hw[ky * 3 + 2] = row[2];
        }
        const int* thr = g_thr2 + half * 32;
        for (int oc = 0; oc < 32; ++oc) {
            int m = 0;
#pragma unroll
            for (int tt = 0; tt < 9; ++tt)
                m += __popc(hw[tt] ^ wp[oc * 9 + tt]);
            outw |= (m < thr[oc] ? 1u : 0u) << oc;
        }
        outw ^= g_pol2[half];
    } else {
        uint32_t hw[9];
        bool tv[9];
        int nvt = 0;
#pragma unroll
        for (int ky = 0; ky < 3; ++ky) {
            int iy = 2 * oy - 1 + ky;
            bool vy = (iy >= 0 && iy < 224);
#pragma unroll
            for (int kx = 0; kx < 3; ++kx) {
                int ix = 2 * ox - 1 + kx;
                bool v = vy && (ix >= 0) && (ix < 224);
                int tt = ky * 3 + kx;
                tv[tt] = v;
                nvt += v ? 1 : 0;
                hw[tt] = v ? hb[iy * 224 + ix] : 0u;
            }
        }
        int base = 32 * nvt;
        const float* invp = g_inv2 + half * 32;
        const float* shp  = g_sh2  + half * 32;
        for (int oc = 0; oc < 32; ++oc) {
            int s = 0;
#pragma unroll
            for (int tt = 0; tt < 9; ++tt) {
                uint32_t w = wp[oc * 9 + tt];
                s += __popc(hw[tt] ^ (tv[tt] ? w : 0u));
            }
            int val = base - 2 * s;
            float y = __fadd_rn(__fmul_rn((float)val, invp[oc]), shp[oc]);
            outw |= (y < 0.0f ? 1u : 0u) << oc;
        }
    }
    if (half == 0) g_h2lo[idx] = outw; else g_h2hi[idx] = outw;
}

// ---------- layer 3 + avgpool reduce + (last block) FC ----------------------
// grid (49, 32, 4), block 64: one wave per 64 pixels of one (b, ocq)
__global__ void layer3_kernel(
    const float* __restrict__ fcw, const float* __restrict__ fcb,
    float* __restrict__ out)
{
    int ocq = blockIdx.z;
    int b = blockIdx.y;
    int lane = threadIdx.x;
    int pix = blockIdx.x * 64 + lane;     // 0..3135, always valid (49*64)
    int oy = pix / 56;
    int ox = pix % 56;

    const uint32_t* hlo = g_h2lo + (size_t)b * 112 * 112;
    const uint32_t* hhi = g_h2hi + (size_t)b * 112 * 112;
    uint64_t hw[9];
    bool tv[9];
    int nvt = 0;
#pragma unroll
    for (int ky = 0; ky < 3; ++ky) {
        int iy = 2 * oy - 1 + ky;
        bool vy = (iy >= 0 && iy < 112);
#pragma unroll
        for (int kx = 0; kx < 3; ++kx) {
            int ix = 2 * ox - 1 + kx;
            bool v = vy && (ix >= 0) && (ix < 112);
            int tt = ky * 3 + kx;
            tv[tt] = v;
            nvt += v ? 1 : 0;
            hw[tt] = v ? ((uint64_t)hlo[iy * 112 + ix] | ((uint64_t)hhi[iy * 112 + ix] << 32)) : 0ull;
        }
    }
    int base = 64 * nvt;

    const uint64_t* wp = g_w3p + ocq * 288;
    const float* invp = g_inv3 + ocq * 32;
    const float* shp  = g_sh3  + ocq * 32;
    for (int oc = 0; oc < 32; ++oc) {
        int s = 0;
#pragma unroll
        for (int tt = 0; tt < 9; ++tt) {
            uint64_t w = wp[oc * 9 + tt];
            s += __popcll(hw[tt] ^ (tv[tt] ? w : 0ull));
        }
        int val = base - 2 * s;
        float y = __fadd_rn(__fmul_rn((float)val, invp[oc]), shp[oc]);
        unsigned long long bm = __ballot(y < 0.0f ? 1 : 0);
        if (lane == 0) {
            int cneg = __popcll(bm);
            atomicAdd(&g_acc[b * 128 + ocq * 32 + oc], 64 - 2 * cneg);
        }
    }

    // last-block FC
    __threadfence();
    int prev = 0;
    if (lane == 0)
        prev = __hip_atomic_fetch_add(&g_done, 1, __ATOMIC_ACQ_REL, __HIP_MEMORY_SCOPE_AGENT);
    prev = __shfl(prev, 0);
    if (prev == 49 * 32 * 4 - 1) {
        int bb = lane >> 1, k = lane & 1;
        float s = fcb[k];
        for (int oc = 0; oc < 128; ++oc) {
            int a = __hip_atomic_load(&g_acc[bb * 128 + oc], __ATOMIC_RELAXED, __HIP_MEMORY_SCOPE_AGENT);
            float h = __fdiv_rn((float)a, 3136.0f);
            s = __fadd_rn(s, __fmul_rn(h, fcw[k * 128 + oc]));
        }
        out[bb * 2 + k] = s;
    }
}

// ---------------------------------------------------------------------------
extern "C" void kernel_launch(void* const* d_in, const int* in_sizes, int n_in,
                              void* d_out, int out_size, void* d_ws, size_t ws_size,
                              hipStream_t stream)
{
    const float* x   = (const float*)d_in[0];
    const float* w1  = (const float*)d_in[1];
    const float* w2  = (const float*)d_in[2];
    const float* w3  = (const float*)d_in[3];
    const float* g1  = (const float*)d_in[4];
    const float* b1  = (const float*)d_in[5];
    const float* m1  = (const float*)d_in[6];
    const float* v1  = (const float*)d_in[7];
    const float* g2  = (const float*)d_in[8];
    const float* b2  = (const float*)d_in[9];
    const float* m2  = (const float*)d_in[10];
    const float* v2  = (const float*)d_in[11];
    const float* g3  = (const float*)d_in[12];
    const float* b3  = (const float*)d_in[13];
    const float* m3  = (const float*)d_in[14];
    const float* v3  = (const float*)d_in[15];
    const float* fcw = (const float*)d_in[16];
    const float* fcb = (const float*)d_in[17];
    float* out = (float*)d_out;
    (void)d_ws; (void)ws_size; (void)in_sizes; (void)n_in; (void)out_size;

    prep_kernel<<<16, 256, 0, stream>>>(w1, w2, w3,
        g1, b1, m1, v1, g2, b2, m2, v2, g3, b3, m3, v3);

    {   // layer 1: 4 px/thread
        int total = 32 * 224 * 56;
        layer1_kernel<<<(total + 255) / 256, 256, 0, stream>>>(x);
    }
    {   // layer 2
        int total = 32 * 112 * 112;
        dim3 grid((total + 255) / 256, 2);
        layer2_kernel<<<grid, 256, 0, stream>>>();
    }
    {   // layer 3 + pool + fc
        dim3 grid(49, 32, 4);
        layer3_kernel<<<grid, 64, 0, stream>>>(fcw, fcb, out);
    }
}

// Round 8
// 233.659 us; speedup vs baseline: 1.7272x; 1.7272x over previous
//
#include <hip/hip_runtime.h>
#include <cstdint>
#include <cstddef>

// ---------------------------------------------------------------------------
// BNN classifier: 3x binarized conv+BN+sign, avgpool, FC.
// Exact integer XNOR-popcount; interior pixels use exact precomputed integer
// thresholds (scan of the monotone fp32 BN curve with identical __f*_rn ops).
// R8: revert layer3 to R5 shape (256-thr blocks, plain atomicAdd, NO per-block
//     device fence — R7's fence cost 200us); keep R7 layer1/layer2; fc separate.
// ---------------------------------------------------------------------------

__device__ __align__(16) uint32_t g_h1p[32 * 224 * 224];
__device__ __align__(16) uint32_t g_h2lo[32 * 112 * 112];
__device__ __align__(16) uint32_t g_h2hi[32 * 112 * 112];
__device__ uint32_t g_w1p[32];
__device__ uint32_t g_w2p[576];
__device__ uint64_t g_w3p[1152];
__device__ float    g_inv1[32],  g_sh1[32];
__device__ float    g_inv2[64],  g_sh2[64];
__device__ float    g_inv3[128], g_sh3[128];
__device__ int      g_thr1[32];    // interior mismatch thresholds (nvalid=27)
__device__ uint32_t g_pol1;
__device__ int      g_thr2[64];    // interior thresholds (base=288)
__device__ uint32_t g_pol2[2];
__device__ int      g_acc[32 * 128];

__device__ __forceinline__ int bn_neg(int s, float inv, float sh) {
    float y = __fadd_rn(__fmul_rn((float)s, inv), sh);
    return (y < 0.0f) ? 1 : 0;
}

// ---------- prep ------------------------------------------------------------
__global__ void prep_kernel(
    const float* __restrict__ w1, const float* __restrict__ w2, const float* __restrict__ w3,
    const float* __restrict__ g1, const float* __restrict__ b1, const float* __restrict__ m1, const float* __restrict__ v1,
    const float* __restrict__ g2, const float* __restrict__ b2, const float* __restrict__ m2, const float* __restrict__ v2,
    const float* __restrict__ g3, const float* __restrict__ b3, const float* __restrict__ m3, const float* __restrict__ v3)
{
    int tid = blockIdx.x * blockDim.x + threadIdx.x;
    int lt  = threadIdx.x;

    if (tid < 32 * 128) g_acc[tid] = 0;

    // ---- weight packing (any block) ----
    if (tid < 32) {
        uint32_t m = 0;
        for (int t = 0; t < 27; ++t)
            m |= (w1[tid * 27 + t] < 0.0f ? 1u : 0u) << t;
        g_w1p[tid] = m;
    }
    if (tid < 576) {
        int oc = tid / 9, tap = tid % 9, ky = tap / 3, kx = tap % 3;
        uint32_t m = 0;
        for (int ic = 0; ic < 32; ++ic)
            m |= (w2[((oc * 32 + ic) * 3 + ky) * 3 + kx] < 0.0f ? 1u : 0u) << ic;
        g_w2p[tid] = m;
    }
    if (tid < 1152) {
        int oc = tid / 9, tap = tid % 9, ky = tap / 3, kx = tap % 3;
        uint64_t m = 0;
        for (int ic = 0; ic < 64; ++ic)
            m |= (uint64_t)(w3[((oc * 64 + ic) * 3 + ky) * 3 + kx] < 0.0f ? 1u : 0u) << ic;
        g_w3p[tid] = m;
    }

    // ---- BN tables + thresholds: block 0 only (needs intra-block sync) ----
    if (blockIdx.x == 0) {
        if (lt < 32) {
            float inv = __fdiv_rn(g1[lt], __fsqrt_rn(__fadd_rn(v1[lt], 1e-5f)));
            g_inv1[lt] = inv;
            g_sh1[lt] = __fsub_rn(b1[lt], __fmul_rn(m1[lt], inv));
        } else if (lt < 96) {
            int c = lt - 32;
            float inv = __fdiv_rn(g2[c], __fsqrt_rn(__fadd_rn(v2[c], 1e-5f)));
            g_inv2[c] = inv;
            g_sh2[c] = __fsub_rn(b2[c], __fmul_rn(m2[c], inv));
        } else if (lt < 224) {
            int c = lt - 96;
            float inv = __fdiv_rn(g3[c], __fsqrt_rn(__fadd_rn(v3[c], 1e-5f)));
            g_inv3[c] = inv;
            g_sh3[c] = __fsub_rn(b3[c], __fmul_rn(m3[c], inv));
        }
        __syncthreads();

        __shared__ uint32_t p1bits[32];
        __shared__ uint32_t p2bits[64];
        if (lt < 32) {  // layer1 interior: s = 27 - 2m, m in 0..27
            float inv = g_inv1[lt], sh = g_sh1[lt];
            int P = bn_neg(27 - 2 * 27, inv, sh);
            int M = 28;
            for (int m = 0; m <= 27; ++m)
                if (bn_neg(27 - 2 * m, inv, sh) == P) { M = m; break; }
            g_thr1[lt] = M;
            p1bits[lt] = (uint32_t)P;
        }
        if (lt >= 64 && lt < 128) {  // layer2 interior: s = 288 - 2m
            int c = lt - 64;
            float inv = g_inv2[c], sh = g_sh2[c];
            int P = bn_neg(288 - 2 * 288, inv, sh);
            int M = 289;
            for (int m = 0; m <= 288; ++m)
                if (bn_neg(288 - 2 * m, inv, sh) == P) { M = m; break; }
            g_thr2[c] = M;
            p2bits[c] = (uint32_t)P;
        }
        __syncthreads();
        if (lt == 0) {
            uint32_t p = 0;
            for (int i = 0; i < 32; ++i) p |= p1bits[i] << i;
            g_pol1 = p;
            uint32_t plo = 0, phi = 0;
            for (int i = 0; i < 32; ++i) { plo |= p2bits[i] << i; phi |= p2bits[32 + i] << i; }
            g_pol2[0] = plo; g_pol2[1] = phi;
        }
    }
}

// ---------- layer 1: 4 pixels/thread ---------------------------------------
__global__ void layer1_kernel(const float* __restrict__ x)
{
    int idx = blockIdx.x * blockDim.x + threadIdx.x;
    const int total = 32 * 224 * 56;
    if (idx >= total) return;
    int xq = idx % 56;
    int t  = idx / 56;
    int yy = t % 224;
    int b  = t / 224;
    int xx0 = xq * 4;

    const float* xb = x + (size_t)b * 3 * 224 * 224;
    uint32_t outw[4];

    bool interior = (yy >= 1) && (yy <= 222) && (xq >= 1) && (xq <= 54);
    if (interior) {
        // 6 column-sign bits per (channel,row), shared by the 4 pixels
        uint32_t cb[3][3];
#pragma unroll
        for (int ic = 0; ic < 3; ++ic)
#pragma unroll
        for (int r = 0; r < 3; ++r) {
            const float* p = xb + ((size_t)ic * 224 + (yy - 1 + r)) * 224 + (xx0 - 1);
            uint32_t bits = 0;
#pragma unroll
            for (int j = 0; j < 6; ++j)
                bits |= (p[j] < 0.0f ? 1u : 0u) << j;
            cb[ic][r] = bits;
        }
        uint32_t xm[4];
#pragma unroll
        for (int p = 0; p < 4; ++p) {
            uint32_t m = 0;
#pragma unroll
            for (int ic = 0; ic < 3; ++ic)
#pragma unroll
            for (int r = 0; r < 3; ++r)
                m |= ((cb[ic][r] >> p) & 7u) << (ic * 9 + r * 3);
            xm[p] = m;
        }
#pragma unroll
        for (int p = 0; p < 4; ++p) outw[p] = 0;
#pragma unroll
        for (int oc = 0; oc < 32; ++oc) {
            uint32_t w = g_w1p[oc];          // uniform -> scalar
            int M = g_thr1[oc];
#pragma unroll
            for (int p = 0; p < 4; ++p) {
                int mm = __popc(xm[p] ^ w);
                outw[p] |= (mm < M ? 1u : 0u) << oc;
            }
        }
        uint32_t pol = g_pol1;
#pragma unroll
        for (int p = 0; p < 4; ++p) outw[p] ^= pol;
    } else {
        // border quad: exact per-pixel float path (R5 math)
#pragma unroll
        for (int p = 0; p < 4; ++p) {
            int xx = xx0 + p;
            uint32_t xmask = 0, vmask = 0;
#pragma unroll
            for (int ky = 0; ky < 3; ++ky) {
                int iy = yy - 1 + ky;
                bool vy = (iy >= 0 && iy < 224);
#pragma unroll
                for (int kx = 0; kx < 3; ++kx) {
                    int ix = xx - 1 + kx;
                    bool v = vy && (ix >= 0) && (ix < 224);
                    if (v) {
                        int sp = ky * 3 + kx;
#pragma unroll
                        for (int ic = 0; ic < 3; ++ic) {
                            float val = xb[((size_t)ic * 224 + iy) * 224 + ix];
                            xmask |= (val < 0.0f ? 1u : 0u) << (ic * 9 + sp);
                            vmask |= 1u << (ic * 9 + sp);
                        }
                    }
                }
            }
            int nvalid = __popc(vmask);
            uint32_t ow = 0;
#pragma unroll
            for (int oc = 0; oc < 32; ++oc) {
                int mism = __popc((xmask ^ g_w1p[oc]) & vmask);
                int s = nvalid - 2 * mism;
                float y = __fadd_rn(__fmul_rn((float)s, g_inv1[oc]), g_sh1[oc]);
                ow |= (y < 0.0f ? 1u : 0u) << oc;
            }
            outw[p] = ow;
        }
    }
    uint4 o = make_uint4(outw[0], outw[1], outw[2], outw[3]);
    *(uint4*)&g_h1p[((size_t)b * 224 + yy) * 224 + xx0] = o;
}

// ---------- layer 2 ---------------------------------------------------------
__global__ void layer2_kernel()
{
    int half = blockIdx.y;
    int idx = blockIdx.x * blockDim.x + threadIdx.x;
    const int total = 32 * 112 * 112;
    if (idx >= total) return;
    int ox = idx % 112;
    int t = idx / 112;
    int oy = t % 112;
    int b = t / 112;

    const uint32_t* hb = g_h1p + (size_t)b * 224 * 224;
    const uint32_t* wp = g_w2p + half * 288;
    uint32_t outw = 0;

    if (ox >= 1 && oy >= 1) {
        uint32_t hw[9];
#pragma unroll
        for (int ky = 0; ky < 3; ++ky) {
            const uint32_t* row = hb + (2 * oy - 1 + ky) * 224 + (2 * ox - 1);
            hw[ky * 3 + 0] = row[0];
            hw[ky * 3 + 1] = row[1];
            hw[ky * 3 + 2] = row[2];
        }
        const int* thr = g_thr2 + half * 32;
        for (int oc = 0; oc < 32; ++oc) {
            int m = 0;
#pragma unroll
            for (int tt = 0; tt < 9; ++tt)
                m += __popc(hw[tt] ^ wp[oc * 9 + tt]);
            outw |= (m < thr[oc] ? 1u : 0u) << oc;
        }
        outw ^= g_pol2[half];
    } else {
        uint32_t hw[9];
        bool tv[9];
        int nvt = 0;
#pragma unroll
        for (int ky = 0; ky < 3; ++ky) {
            int iy = 2 * oy - 1 + ky;
            bool vy = (iy >= 0 && iy < 224);
#pragma unroll
            for (int kx = 0; kx < 3; ++kx) {
                int ix = 2 * ox - 1 + kx;
                bool v = vy && (ix >= 0) && (ix < 224);
                int tt = ky * 3 + kx;
                tv[tt] = v;
                nvt += v ? 1 : 0;
                hw[tt] = v ? hb[iy * 224 + ix] : 0u;
            }
        }
        int base = 32 * nvt;
        const float* invp = g_inv2 + half * 32;
        const float* shp  = g_sh2  + half * 32;
        for (int oc = 0; oc < 32; ++oc) {
            int s = 0;
#pragma unroll
            for (int tt = 0; tt < 9; ++tt) {
                uint32_t w = wp[oc * 9 + tt];
                s += __popc(hw[tt] ^ (tv[tt] ? w : 0u));
            }
            int val = base - 2 * s;
            float y = __fadd_rn(__fmul_rn((float)val, invp[oc]), shp[oc]);
            outw |= (y < 0.0f ? 1u : 0u) << oc;
        }
    }
    if (half == 0) g_h2lo[idx] = outw; else g_h2hi[idx] = outw;
}

// ---------- layer 3 + avgpool reduce (R5 shape: 256-thr, plain atomics) -----
// grid (13, 32, 4): blockIdx.z = oc quarter; ballot+atomic into g_acc[b][oc]
__global__ void layer3_kernel()
{
    int ocq = blockIdx.z;
    int b = blockIdx.y;
    int pix = blockIdx.x * blockDim.x + threadIdx.x;
    bool valid = pix < 56 * 56;
    int oy = valid ? pix / 56 : 0;
    int ox = valid ? pix % 56 : 0;

    const uint32_t* hlo = g_h2lo + (size_t)b * 112 * 112;
    const uint32_t* hhi = g_h2hi + (size_t)b * 112 * 112;
    uint64_t hw[9];
    bool tv[9];
    int nvt = 0;
#pragma unroll
    for (int ky = 0; ky < 3; ++ky) {
        int iy = 2 * oy - 1 + ky;
        bool vy = (iy >= 0 && iy < 112);
#pragma unroll
        for (int kx = 0; kx < 3; ++kx) {
            int ix = 2 * ox - 1 + kx;
            bool v = valid && vy && (ix >= 0) && (ix < 112);
            int tt = ky * 3 + kx;
            tv[tt] = v;
            nvt += v ? 1 : 0;
            hw[tt] = v ? ((uint64_t)hlo[iy * 112 + ix] | ((uint64_t)hhi[iy * 112 + ix] << 32)) : 0ull;
        }
    }
    int base = 64 * nvt;
    int lane = threadIdx.x & 63;
    unsigned long long am = __ballot(valid ? 1 : 0);
    int nact = __popcll(am);

    const uint64_t* wp = g_w3p + ocq * 288;
    const float* invp = g_inv3 + ocq * 32;
    const float* shp  = g_sh3  + ocq * 32;
    for (int oc = 0; oc < 32; ++oc) {
        int s = 0;
#pragma unroll
        for (int tt = 0; tt < 9; ++tt) {
            uint64_t w = wp[oc * 9 + tt];           // uniform -> s_load
            s += __popcll(hw[tt] ^ (tv[tt] ? w : 0ull));
        }
        int val = base - 2 * s;
        float y = __fadd_rn(__fmul_rn((float)val, invp[oc]), shp[oc]);
        int neg = (valid && y < 0.0f) ? 1 : 0;
        unsigned long long bm = __ballot(neg);
        if (lane == 0) {
            int cneg = __popcll(bm);
            atomicAdd(&g_acc[b * 128 + ocq * 32 + oc], nact - 2 * cneg);
        }
    }
}

// ---------- final: mean + fc ------------------------------------------------
__global__ void fc_kernel(
    const float* __restrict__ fc_w, const float* __restrict__ fc_b,
    float* __restrict__ out)
{
    int tid = threadIdx.x;
    if (tid >= 64) return;
    int b = tid >> 1, k = tid & 1;
    float s = fc_b[k];
    for (int oc = 0; oc < 128; ++oc) {
        float h = __fdiv_rn((float)g_acc[b * 128 + oc], 3136.0f);
        s = __fadd_rn(s, __fmul_rn(h, fc_w[k * 128 + oc]));
    }
    out[b * 2 + k] = s;
}

// ---------------------------------------------------------------------------
extern "C" void kernel_launch(void* const* d_in, const int* in_sizes, int n_in,
                              void* d_out, int out_size, void* d_ws, size_t ws_size,
                              hipStream_t stream)
{
    const float* x   = (const float*)d_in[0];
    const float* w1  = (const float*)d_in[1];
    const float* w2  = (const float*)d_in[2];
    const float* w3  = (const float*)d_in[3];
    const float* g1  = (const float*)d_in[4];
    const float* b1  = (const float*)d_in[5];
    const float* m1  = (const float*)d_in[6];
    const float* v1  = (const float*)d_in[7];
    const float* g2  = (const float*)d_in[8];
    const float* b2  = (const float*)d_in[9];
    const float* m2  = (const float*)d_in[10];
    const float* v2  = (const float*)d_in[11];
    const float* g3  = (const float*)d_in[12];
    const float* b3  = (const float*)d_in[13];
    const float* m3  = (const float*)d_in[14];
    const float* v3  = (const float*)d_in[15];
    const float* fcw = (const float*)d_in[16];
    const float* fcb = (const float*)d_in[17];
    float* out = (float*)d_out;
    (void)d_ws; (void)ws_size; (void)in_sizes; (void)n_in; (void)out_size;

    prep_kernel<<<16, 256, 0, stream>>>(w1, w2, w3,
        g1, b1, m1, v1, g2, b2, m2, v2, g3, b3, m3, v3);

    {   // layer 1: 4 px/thread
        int total = 32 * 224 * 56;
        layer1_kernel<<<(total + 255) / 256, 256, 0, stream>>>(x);
    }
    {   // layer 2
        int total = 32 * 112 * 112;
        dim3 grid((total + 255) / 256, 2);
        layer2_kernel<<<grid, 256, 0, stream>>>();
    }
    {   // layer 3 + pool reduce
        dim3 grid((56 * 56 + 255) / 256, 32, 4);
        layer3_kernel<<<grid, 256, 0, stream>>>();
    }
    // fc
    fc_kernel<<<1, 64, 0, stream>>>(fcw, fcb, out);
}

// Round 9
// 221.979 us; speedup vs baseline: 1.8181x; 1.0526x over previous
//
#include <hip/hip_runtime.h>
#include <cstdint>
#include <cstddef>

// ---------------------------------------------------------------------------
// BNN classifier: 3x binarized conv+BN+sign, avgpool, FC.
// Exact integer XNOR-popcount. Layers 1&2 use per-(pattern,oc) integer
// thresholds valid for ALL border classes (monotone fp32 BN scan in prep),
// with interior/border split at BLOCK granularity -> zero wave divergence.
// R9: fixes R7/R8's layer1 divergence regression (every wave ran both paths).
// ---------------------------------------------------------------------------

__device__ __align__(16) uint32_t g_h1p[32 * 224 * 224];
__device__ __align__(16) uint32_t g_h2lo[32 * 112 * 112];
__device__ __align__(16) uint32_t g_h2hi[32 * 112 * 112];
__device__ uint32_t g_w1p[32];
__device__ uint32_t g_w2p[576];
__device__ uint64_t g_w3p[1152];
__device__ float    g_inv1[32],  g_sh1[32];
__device__ float    g_inv2[64],  g_sh2[64];
__device__ float    g_inv3[128], g_sh3[128];
__device__ int      g_Mb1[9 * 32];     // layer1 thresholds per (pattern,oc)
__device__ uint32_t g_pol1pk[9];       // layer1 polarity words per pattern
__device__ int      g_Mb2[4 * 64];     // layer2 thresholds per (pattern,oc)
__device__ uint32_t g_pol2pk[4 * 2];   // layer2 polarity words per (pattern,half)
__device__ int      g_acc[32 * 128];

__device__ __forceinline__ int bn_neg(int s, float inv, float sh) {
    float y = __fadd_rn(__fmul_rn((float)s, inv), sh);
    return (y < 0.0f) ? 1 : 0;
}

// ---------- prep ------------------------------------------------------------
__global__ void prep_kernel(
    const float* __restrict__ w1, const float* __restrict__ w2, const float* __restrict__ w3,
    const float* __restrict__ g1, const float* __restrict__ b1, const float* __restrict__ m1, const float* __restrict__ v1,
    const float* __restrict__ g2, const float* __restrict__ b2, const float* __restrict__ m2, const float* __restrict__ v2,
    const float* __restrict__ g3, const float* __restrict__ b3, const float* __restrict__ m3, const float* __restrict__ v3)
{
    int tid = blockIdx.x * blockDim.x + threadIdx.x;
    int lt  = threadIdx.x;

    if (tid < 32 * 128) g_acc[tid] = 0;

    if (tid < 1152) {   // w3: [128][64][3][3] -> w3p[oc*9+tap], bit=ic
        int oc = tid / 9, tap = tid % 9, ky = tap / 3, kx = tap % 3;
        uint64_t m = 0;
        for (int ic = 0; ic < 64; ++ic)
            m |= (uint64_t)(w3[((oc * 64 + ic) * 3 + ky) * 3 + kx] < 0.0f ? 1u : 0u) << ic;
        g_w3p[tid] = m;
    }

    if (blockIdx.x != 0) return;
    // ---------------- block 0: packing + tables ----------------
    for (int i = lt; i < 32; i += 256) {   // w1p
        uint32_t m = 0;
        for (int t = 0; t < 27; ++t)
            m |= (w1[i * 27 + t] < 0.0f ? 1u : 0u) << t;
        g_w1p[i] = m;
    }
    for (int i = lt; i < 576; i += 256) {  // w2p
        int oc = i / 9, tap = i % 9, ky = tap / 3, kx = tap % 3;
        uint32_t m = 0;
        for (int ic = 0; ic < 32; ++ic)
            m |= (w2[((oc * 32 + ic) * 3 + ky) * 3 + kx] < 0.0f ? 1u : 0u) << ic;
        g_w2p[i] = m;
    }
    if (lt < 32) {
        float inv = __fdiv_rn(g1[lt], __fsqrt_rn(__fadd_rn(v1[lt], 1e-5f)));
        g_inv1[lt] = inv;
        g_sh1[lt] = __fsub_rn(b1[lt], __fmul_rn(m1[lt], inv));
    } else if (lt < 96) {
        int c = lt - 32;
        float inv = __fdiv_rn(g2[c], __fsqrt_rn(__fadd_rn(v2[c], 1e-5f)));
        g_inv2[c] = inv;
        g_sh2[c] = __fsub_rn(b2[c], __fmul_rn(m2[c], inv));
    } else if (lt < 224) {
        int c = lt - 96;
        float inv = __fdiv_rn(g3[c], __fsqrt_rn(__fadd_rn(v3[c], 1e-5f)));
        g_inv3[c] = inv;
        g_sh3[c] = __fsub_rn(b3[c], __fmul_rn(m3[c], inv));
    }
    __syncthreads();

    // monotone-scan thresholds per nvalid class (exact: same __f*_rn ops)
    __shared__ int sM1[3][32], sP1[3][32];
    __shared__ int sM2[3][64], sP2[3][64];
    if (lt < 32) {
        int oc = lt;
        float inv = g_inv1[oc], sh = g_sh1[oc];
        const int nvs[3] = {12, 18, 27};
        for (int k = 0; k < 3; ++k) {
            int nv = nvs[k];
            int P = bn_neg(-nv, inv, sh);
            int M = nv + 1;
            for (int m = 0; m <= nv; ++m)
                if (bn_neg(nv - 2 * m, inv, sh) == P) { M = m; break; }
            sM1[k][oc] = M; sP1[k][oc] = P;
        }
    } else if (lt >= 64 && lt < 128) {
        int oc = lt - 64;
        float inv = g_inv2[oc], sh = g_sh2[oc];
        const int nvs[3] = {128, 192, 288};
        for (int k = 0; k < 3; ++k) {
            int nv = nvs[k];
            int P = bn_neg(-nv, inv, sh);
            int M = nv + 1;
            for (int m = 0; m <= nv; ++m)
                if (bn_neg(nv - 2 * m, inv, sh) == P) { M = m; break; }
            sM2[k][oc] = M; sP2[k][oc] = P;
        }
    }
    __syncthreads();

    // layer1: 9 patterns (py*3+px), fold popc(w & invmask) into threshold
    if (lt < 288) {
        int pat = lt / 32, oc = lt % 32;
        int py = pat / 3, px = pat % 3;
        uint32_t invm = 0;
        for (int ic = 0; ic < 3; ++ic)
            for (int r = 0; r < 3; ++r)
                for (int c = 0; c < 3; ++c) {
                    bool inval = (py == 0 && r == 0) || (py == 2 && r == 2) ||
                                 (px == 0 && c == 0) || (px == 2 && c == 2);
                    if (inval) invm |= 1u << (ic * 9 + r * 3 + c);
                }
        int nv = 3 * (3 - (py != 1 ? 1 : 0)) * (3 - (px != 1 ? 1 : 0));
        int cls = (nv == 27) ? 2 : ((nv == 18) ? 1 : 0);
        g_Mb1[pat * 32 + oc] = sM1[cls][oc] + __popc(g_w1p[oc] & invm);
    }
    // layer2: 4 patterns (0=int,1=top,2=left,3=topleft)
    {
        int pat = lt / 64, oc = lt % 64;   // lt<256 covers all
        uint32_t tm = (pat == 0) ? 0u : (pat == 1 ? 0x07u : (pat == 2 ? 0x49u : 0x4Fu));
        int cls = (pat == 0) ? 2 : (pat == 3 ? 0 : 1);
        int corr = 0;
        for (int tt = 0; tt < 9; ++tt)
            if ((tm >> tt) & 1) corr += __popc(g_w2p[oc * 9 + tt]);
        g_Mb2[pat * 64 + oc] = sM2[cls][oc] + corr;
    }
    if (lt == 0) {
        for (int pat = 0; pat < 9; ++pat) {
            int py = pat / 3, px = pat % 3;
            int nv = 3 * (3 - (py != 1 ? 1 : 0)) * (3 - (px != 1 ? 1 : 0));
            int cls = (nv == 27) ? 2 : ((nv == 18) ? 1 : 0);
            uint32_t p = 0;
            for (int i = 0; i < 32; ++i) p |= (uint32_t)sP1[cls][i] << i;
            g_pol1pk[pat] = p;
        }
        for (int pat = 0; pat < 4; ++pat) {
            int cls = (pat == 0) ? 2 : (pat == 3 ? 0 : 1);
            uint32_t plo = 0, phi = 0;
            for (int i = 0; i < 32; ++i) {
                plo |= (uint32_t)sP2[cls][i] << i;
                phi |= (uint32_t)sP2[cls][32 + i] << i;
            }
            g_pol2pk[pat * 2 + 0] = plo;
            g_pol2pk[pat * 2 + 1] = phi;
        }
    }
}

// ---------- layer 1: block-split interior quads / border pixels -------------
#define L1_NBI 1499   // ceil(32*222*54 / 256)
__global__ void layer1_kernel(const float* __restrict__ x)
{
    if (blockIdx.x < L1_NBI) {
        // interior quads: yy in [1,222], xq in [1,54] (xx in [4,219])
        int idx = blockIdx.x * 256 + threadIdx.x;
        if (idx >= 32 * 222 * 54) return;
        int t = idx;
        int xq = 1 + t % 54; t /= 54;
        int yy = 1 + t % 222;
        int b  = t / 222;
        int xx0 = xq * 4;

        const float* xb = x + (size_t)b * 3 * 224 * 224;
        uint32_t cb[3][3];
#pragma unroll
        for (int ic = 0; ic < 3; ++ic)
#pragma unroll
        for (int r = 0; r < 3; ++r) {
            const float4* f = (const float4*)(xb + ((size_t)ic * 224 + (yy - 1 + r)) * 224 + (xx0 - 4));
            float4 a = f[0], m = f[1], c = f[2];
            uint32_t bits =  (a.w < 0.0f ? 1u : 0u)
                          | ((m.x < 0.0f ? 1u : 0u) << 1)
                          | ((m.y < 0.0f ? 1u : 0u) << 2)
                          | ((m.z < 0.0f ? 1u : 0u) << 3)
                          | ((m.w < 0.0f ? 1u : 0u) << 4)
                          | ((c.x < 0.0f ? 1u : 0u) << 5);
            cb[ic][r] = bits;
        }
        uint32_t xm[4];
#pragma unroll
        for (int p = 0; p < 4; ++p) {
            uint32_t m = 0;
#pragma unroll
            for (int ic = 0; ic < 3; ++ic)
#pragma unroll
            for (int r = 0; r < 3; ++r)
                m |= ((cb[ic][r] >> p) & 7u) << (ic * 9 + r * 3);
            xm[p] = m;
        }
        uint32_t outw[4] = {0, 0, 0, 0};
#pragma unroll
        for (int oc = 0; oc < 32; ++oc) {
            uint32_t w = g_w1p[oc];           // uniform -> scalar
            int M = g_Mb1[4 * 32 + oc];       // interior pattern = 4
#pragma unroll
            for (int p = 0; p < 4; ++p) {
                int mm = __popc(xm[p] ^ w);
                outw[p] |= (mm < M ? 1u : 0u) << oc;
            }
        }
        uint32_t pol = g_pol1pk[4];
        uint4 o = make_uint4(outw[0] ^ pol, outw[1] ^ pol, outw[2] ^ pol, outw[3] ^ pol);
        *(uint4*)&g_h1p[((size_t)b * 224 + yy) * 224 + xx0] = o;
    } else {
        // border pixels, 1/thread: 32 * 2224 = 71168 = 278*256 exactly
        int i = (blockIdx.x - L1_NBI) * 256 + threadIdx.x;
        int b = i / 2224;
        int r = i % 2224;
        int yy, xx;
        if (r < 448) { yy = (r < 224) ? 0 : 223; xx = r % 224; }
        else { int r2 = r - 448; yy = 1 + (r2 >> 3); int k = r2 & 7; xx = (k < 4) ? k : (216 + k); }

        const float* xb = x + (size_t)b * 3 * 224 * 224;
        uint32_t xmask = 0;
#pragma unroll
        for (int ky = 0; ky < 3; ++ky) {
            int iy = yy - 1 + ky;
            if (iy < 0 || iy > 223) continue;
#pragma unroll
            for (int kx = 0; kx < 3; ++kx) {
                int ix = xx - 1 + kx;
                if (ix < 0 || ix > 223) continue;
                int sp = ky * 3 + kx;
#pragma unroll
                for (int ic = 0; ic < 3; ++ic) {
                    float v = xb[((size_t)ic * 224 + iy) * 224 + ix];
                    xmask |= (v < 0.0f ? 1u : 0u) << (ic * 9 + sp);
                }
            }
        }
        int py = (yy == 0) ? 0 : ((yy == 223) ? 2 : 1);
        int px = (xx == 0) ? 0 : ((xx == 223) ? 2 : 1);
        int pat = py * 3 + px;
        uint32_t ow = 0;
        for (int oc = 0; oc < 32; ++oc) {
            uint32_t w = g_w1p[oc];
            int mm = __popc(xmask ^ w);       // invalid bits add popc(w&inv), folded in Mb1
            int thr = g_Mb1[pat * 32 + oc];
            ow |= (mm < thr ? 1u : 0u) << oc;
        }
        ow ^= g_pol1pk[pat];
        g_h1p[((size_t)b * 224 + yy) * 224 + xx] = ow;
    }
}

// ---------- layer 2: block-split interior / border --------------------------
#define L2_NBI 3081   // ceil(32*2*111*111 / 256)
__global__ void layer2_kernel()
{
    if (blockIdx.x < L2_NBI) {
        int idx = blockIdx.x * 256 + threadIdx.x;
        if (idx >= 32 * 2 * 111 * 111) return;
        int t = idx;
        int ox = 1 + t % 111; t /= 111;
        int oy = 1 + t % 111; t /= 111;
        int half = t & 1;
        int b = t >> 1;

        const uint32_t* hb = g_h1p + (size_t)b * 224 * 224;
        uint32_t hw[9];
#pragma unroll
        for (int ky = 0; ky < 3; ++ky) {
            const uint32_t* row = hb + (2 * oy - 1 + ky) * 224 + (2 * ox - 1);
            hw[ky * 3 + 0] = row[0];
            hw[ky * 3 + 1] = row[1];
            hw[ky * 3 + 2] = row[2];
        }
        const uint32_t* wp = g_w2p + half * 288;
        const int* thr = g_Mb2 + half * 32;   // pattern 0
        uint32_t ow = 0;
        for (int oc = 0; oc < 32; ++oc) {
            int mm = 0;
#pragma unroll
            for (int tt = 0; tt < 9; ++tt)
                mm += __popc(hw[tt] ^ wp[oc * 9 + tt]);
            ow |= (mm < thr[oc] ? 1u : 0u) << oc;
        }
        ow ^= g_pol2pk[half];
        uint32_t* dst = half ? g_h2hi : g_h2lo;
        dst[((size_t)b * 112 + oy) * 112 + ox] = ow;
    } else {
        int j = (blockIdx.x - L2_NBI) * 256 + threadIdx.x;
        if (j >= 64 * 223) return;
        int bh = j / 223;
        int r  = j % 223;
        int oy, ox;
        if (r < 112) { oy = 0; ox = r; } else { ox = 0; oy = r - 111; }
        int half = bh & 1, b = bh >> 1;

        const uint32_t* hb = g_h1p + (size_t)b * 224 * 224;
        uint32_t hw[9];
#pragma unroll
        for (int ky = 0; ky < 3; ++ky) {
            int iy = 2 * oy - 1 + ky;
#pragma unroll
            for (int kx = 0; kx < 3; ++kx) {
                int ix = 2 * ox - 1 + kx;
                bool v = (iy >= 0) && (ix >= 0);   // upper bounds always valid
                hw[ky * 3 + kx] = v ? hb[iy * 224 + ix] : 0u;
            }
        }
        int pat = (oy == 0 ? 1 : 0) + (ox == 0 ? 2 : 0);
        const uint32_t* wp = g_w2p + half * 288;
        const int* thr = g_Mb2 + pat * 64 + half * 32;
        uint32_t ow = 0;
        for (int oc = 0; oc < 32; ++oc) {
            int mm = 0;
#pragma unroll
            for (int tt = 0; tt < 9; ++tt)
                mm += __popc(hw[tt] ^ wp[oc * 9 + tt]);
            ow |= (mm < thr[oc] ? 1u : 0u) << oc;
        }
        ow ^= g_pol2pk[pat * 2 + half];
        uint32_t* dst = half ? g_h2hi : g_h2lo;
        dst[((size_t)b * 112 + oy) * 112 + ox] = ow;
    }
}

// ---------- layer 3 + avgpool reduce (R5 shape, plain atomics) --------------
__global__ void layer3_kernel()
{
    int ocq = blockIdx.z;
    int b = blockIdx.y;
    int pix = blockIdx.x * blockDim.x + threadIdx.x;
    bool valid = pix < 56 * 56;
    int oy = valid ? pix / 56 : 0;
    int ox = valid ? pix % 56 : 0;

    const uint32_t* hlo = g_h2lo + (size_t)b * 112 * 112;
    const uint32_t* hhi = g_h2hi + (size_t)b * 112 * 112;
    uint64_t hw[9];
    bool tv[9];
    int nvt = 0;
#pragma unroll
    for (int ky = 0; ky < 3; ++ky) {
        int iy = 2 * oy - 1 + ky;
        bool vy = (iy >= 0 && iy < 112);
#pragma unroll
        for (int kx = 0; kx < 3; ++kx) {
            int ix = 2 * ox - 1 + kx;
            bool v = valid && vy && (ix >= 0) && (ix < 112);
            int tt = ky * 3 + kx;
            tv[tt] = v;
            nvt += v ? 1 : 0;
            hw[tt] = v ? ((uint64_t)hlo[iy * 112 + ix] | ((uint64_t)hhi[iy * 112 + ix] << 32)) : 0ull;
        }
    }
    int base = 64 * nvt;
    int lane = threadIdx.x & 63;
    unsigned long long am = __ballot(valid ? 1 : 0);
    int nact = __popcll(am);

    const uint64_t* wp = g_w3p + ocq * 288;
    const float* invp = g_inv3 + ocq * 32;
    const float* shp  = g_sh3  + ocq * 32;
    for (int oc = 0; oc < 32; ++oc) {
        int s = 0;
#pragma unroll
        for (int tt = 0; tt < 9; ++tt) {
            uint64_t w = wp[oc * 9 + tt];           // uniform -> s_load
            s += __popcll(hw[tt] ^ (tv[tt] ? w : 0ull));
        }
        int val = base - 2 * s;
        float y = __fadd_rn(__fmul_rn((float)val, invp[oc]), shp[oc]);
        int neg = (valid && y < 0.0f) ? 1 : 0;
        unsigned long long bm = __ballot(neg);
        if (lane == 0) {
            int cneg = __popcll(bm);
            atomicAdd(&g_acc[b * 128 + ocq * 32 + oc], nact - 2 * cneg);
        }
    }
}

// ---------- final: mean + fc ------------------------------------------------
__global__ void fc_kernel(
    const float* __restrict__ fc_w, const float* __restrict__ fc_b,
    float* __restrict__ out)
{
    int tid = threadIdx.x;
    if (tid >= 64) return;
    int b = tid >> 1, k = tid & 1;
    float s = fc_b[k];
    for (int oc = 0; oc < 128; ++oc) {
        float h = __fdiv_rn((float)g_acc[b * 128 + oc], 3136.0f);
        s = __fadd_rn(s, __fmul_rn(h, fc_w[k * 128 + oc]));
    }
    out[b * 2 + k] = s;
}

// ---------------------------------------------------------------------------
extern "C" void kernel_launch(void* const* d_in, const int* in_sizes, int n_in,
                              void* d_out, int out_size, void* d_ws, size_t ws_size,
                              hipStream_t stream)
{
    const float* x   = (const float*)d_in[0];
    const float* w1  = (const float*)d_in[1];
    const float* w2  = (const float*)d_in[2];
    const float* w3  = (const float*)d_in[3];
    const float* g1  = (const float*)d_in[4];
    const float* b1  = (const float*)d_in[5];
    const float* m1  = (const float*)d_in[6];
    const float* v1  = (const float*)d_in[7];
    const float* g2  = (const float*)d_in[8];
    const float* b2  = (const float*)d_in[9];
    const float* m2  = (const float*)d_in[10];
    const float* v2  = (const float*)d_in[11];
    const float* g3  = (const float*)d_in[12];
    const float* b3  = (const float*)d_in[13];
    const float* m3  = (const float*)d_in[14];
    const float* v3  = (const float*)d_in[15];
    const float* fcw = (const float*)d_in[16];
    const float* fcb = (const float*)d_in[17];
    float* out = (float*)d_out;
    (void)d_ws; (void)ws_size; (void)in_sizes; (void)n_in; (void)out_size;

    prep_kernel<<<16, 256, 0, stream>>>(w1, w2, w3,
        g1, b1, m1, v1, g2, b2, m2, v2, g3, b3, m3, v3);

    {   // layer 1: interior-quad blocks + border-pixel blocks
        layer1_kernel<<<L1_NBI + 278, 256, 0, stream>>>(x);
    }
    {   // layer 2: interior blocks + border blocks
        layer2_kernel<<<L2_NBI + 56, 256, 0, stream>>>();
    }
    {   // layer 3 + pool reduce
        dim3 grid((56 * 56 + 255) / 256, 32, 4);
        layer3_kernel<<<grid, 256, 0, stream>>>();
    }
    // fc
    fc_kernel<<<1, 64, 0, stream>>>(fcw, fcb, out);
}

// Round 11
// 203.105 us; speedup vs baseline: 1.9870x; 1.0929x over previous
//
#include <hip/hip_runtime.h>
#include <cstdint>
#include <cstddef>

// ---------------------------------------------------------------------------
// BNN classifier: 3x binarized conv+BN+sign, avgpool, FC.
// Exact integer XNOR-popcount. Layers 1&2 use per-(pattern,oc) integer
// thresholds valid for ALL border classes (monotone fp32 BN scan in prep),
// with interior/border split at BLOCK granularity -> zero wave divergence.
// R11 = R10 resubmit (GPU acquisition timeout; kernel never ran):
//      layer2 computes both oc-halves per thread (hw loads shared, 2x ILP);
//      full oc-loop unrolls so weight s_loads pipeline instead of serialize.
// ---------------------------------------------------------------------------

__device__ __align__(16) uint32_t g_h1p[32 * 224 * 224];
__device__ __align__(16) uint32_t g_h2lo[32 * 112 * 112];
__device__ __align__(16) uint32_t g_h2hi[32 * 112 * 112];
__device__ uint32_t g_w1p[32];
__device__ uint32_t g_w2p[576];
__device__ uint64_t g_w3p[1152];
__device__ float    g_inv1[32],  g_sh1[32];
__device__ float    g_inv2[64],  g_sh2[64];
__device__ float    g_inv3[128], g_sh3[128];
__device__ int      g_Mb1[9 * 32];     // layer1 thresholds per (pattern,oc)
__device__ uint32_t g_pol1pk[9];       // layer1 polarity words per pattern
__device__ int      g_Mb2[4 * 64];     // layer2 thresholds per (pattern,oc)
__device__ uint32_t g_pol2pk[4 * 2];   // layer2 polarity words per (pattern,half)
__device__ int      g_acc[32 * 128];

__device__ __forceinline__ int bn_neg(int s, float inv, float sh) {
    float y = __fadd_rn(__fmul_rn((float)s, inv), sh);
    return (y < 0.0f) ? 1 : 0;
}

// ---------- prep ------------------------------------------------------------
__global__ void prep_kernel(
    const float* __restrict__ w1, const float* __restrict__ w2, const float* __restrict__ w3,
    const float* __restrict__ g1, const float* __restrict__ b1, const float* __restrict__ m1, const float* __restrict__ v1,
    const float* __restrict__ g2, const float* __restrict__ b2, const float* __restrict__ m2, const float* __restrict__ v2,
    const float* __restrict__ g3, const float* __restrict__ b3, const float* __restrict__ m3, const float* __restrict__ v3)
{
    int tid = blockIdx.x * blockDim.x + threadIdx.x;
    int lt  = threadIdx.x;

    if (tid < 32 * 128) g_acc[tid] = 0;

    if (tid < 1152) {   // w3: [128][64][3][3] -> w3p[oc*9+tap], bit=ic
        int oc = tid / 9, tap = tid % 9, ky = tap / 3, kx = tap % 3;
        uint64_t m = 0;
        for (int ic = 0; ic < 64; ++ic)
            m |= (uint64_t)(w3[((oc * 64 + ic) * 3 + ky) * 3 + kx] < 0.0f ? 1u : 0u) << ic;
        g_w3p[tid] = m;
    }

    if (blockIdx.x != 0) return;
    // ---------------- block 0: packing + tables ----------------
    for (int i = lt; i < 32; i += 256) {   // w1p
        uint32_t m = 0;
        for (int t = 0; t < 27; ++t)
            m |= (w1[i * 27 + t] < 0.0f ? 1u : 0u) << t;
        g_w1p[i] = m;
    }
    for (int i = lt; i < 576; i += 256) {  // w2p
        int oc = i / 9, tap = i % 9, ky = tap / 3, kx = tap % 3;
        uint32_t m = 0;
        for (int ic = 0; ic < 32; ++ic)
            m |= (w2[((oc * 32 + ic) * 3 + ky) * 3 + kx] < 0.0f ? 1u : 0u) << ic;
        g_w2p[i] = m;
    }
    if (lt < 32) {
        float inv = __fdiv_rn(g1[lt], __fsqrt_rn(__fadd_rn(v1[lt], 1e-5f)));
        g_inv1[lt] = inv;
        g_sh1[lt] = __fsub_rn(b1[lt], __fmul_rn(m1[lt], inv));
    } else if (lt < 96) {
        int c = lt - 32;
        float inv = __fdiv_rn(g2[c], __fsqrt_rn(__fadd_rn(v2[c], 1e-5f)));
        g_inv2[c] = inv;
        g_sh2[c] = __fsub_rn(b2[c], __fmul_rn(m2[c], inv));
    } else if (lt < 224) {
        int c = lt - 96;
        float inv = __fdiv_rn(g3[c], __fsqrt_rn(__fadd_rn(v3[c], 1e-5f)));
        g_inv3[c] = inv;
        g_sh3[c] = __fsub_rn(b3[c], __fmul_rn(m3[c], inv));
    }
    __syncthreads();

    // monotone-scan thresholds per nvalid class (exact: same __f*_rn ops)
    __shared__ int sM1[3][32], sP1[3][32];
    __shared__ int sM2[3][64], sP2[3][64];
    if (lt < 32) {
        int oc = lt;
        float inv = g_inv1[oc], sh = g_sh1[oc];
        const int nvs[3] = {12, 18, 27};
        for (int k = 0; k < 3; ++k) {
            int nv = nvs[k];
            int P = bn_neg(-nv, inv, sh);
            int M = nv + 1;
            for (int m = 0; m <= nv; ++m)
                if (bn_neg(nv - 2 * m, inv, sh) == P) { M = m; break; }
            sM1[k][oc] = M; sP1[k][oc] = P;
        }
    } else if (lt >= 64 && lt < 128) {
        int oc = lt - 64;
        float inv = g_inv2[oc], sh = g_sh2[oc];
        const int nvs[3] = {128, 192, 288};
        for (int k = 0; k < 3; ++k) {
            int nv = nvs[k];
            int P = bn_neg(-nv, inv, sh);
            int M = nv + 1;
            for (int m = 0; m <= nv; ++m)
                if (bn_neg(nv - 2 * m, inv, sh) == P) { M = m; break; }
            sM2[k][oc] = M; sP2[k][oc] = P;
        }
    }
    __syncthreads();

    // layer1: 9 patterns (py*3+px), fold popc(w & invmask) into threshold
    if (lt < 288) {
        int pat = lt / 32, oc = lt % 32;
        int py = pat / 3, px = pat % 3;
        uint32_t invm = 0;
        for (int ic = 0; ic < 3; ++ic)
            for (int r = 0; r < 3; ++r)
                for (int c = 0; c < 3; ++c) {
                    bool inval = (py == 0 && r == 0) || (py == 2 && r == 2) ||
                                 (px == 0 && c == 0) || (px == 2 && c == 2);
                    if (inval) invm |= 1u << (ic * 9 + r * 3 + c);
                }
        int nv = 3 * (3 - (py != 1 ? 1 : 0)) * (3 - (px != 1 ? 1 : 0));
        int cls = (nv == 27) ? 2 : ((nv == 18) ? 1 : 0);
        g_Mb1[pat * 32 + oc] = sM1[cls][oc] + __popc(g_w1p[oc] & invm);
    }
    // layer2: 4 patterns (0=int,1=top,2=left,3=topleft)
    {
        int pat = lt / 64, oc = lt % 64;   // lt<256 covers all
        uint32_t tm = (pat == 0) ? 0u : (pat == 1 ? 0x07u : (pat == 2 ? 0x49u : 0x4Fu));
        int cls = (pat == 0) ? 2 : (pat == 3 ? 0 : 1);
        int corr = 0;
        for (int tt = 0; tt < 9; ++tt)
            if ((tm >> tt) & 1) corr += __popc(g_w2p[oc * 9 + tt]);
        g_Mb2[pat * 64 + oc] = sM2[cls][oc] + corr;
    }
    if (lt == 0) {
        for (int pat = 0; pat < 9; ++pat) {
            int py = pat / 3, px = pat % 3;
            int nv = 3 * (3 - (py != 1 ? 1 : 0)) * (3 - (px != 1 ? 1 : 0));
            int cls = (nv == 27) ? 2 : ((nv == 18) ? 1 : 0);
            uint32_t p = 0;
            for (int i = 0; i < 32; ++i) p |= (uint32_t)sP1[cls][i] << i;
            g_pol1pk[pat] = p;
        }
        for (int pat = 0; pat < 4; ++pat) {
            int cls = (pat == 0) ? 2 : (pat == 3 ? 0 : 1);
            uint32_t plo = 0, phi = 0;
            for (int i = 0; i < 32; ++i) {
                plo |= (uint32_t)sP2[cls][i] << i;
                phi |= (uint32_t)sP2[cls][32 + i] << i;
            }
            g_pol2pk[pat * 2 + 0] = plo;
            g_pol2pk[pat * 2 + 1] = phi;
        }
    }
}

// ---------- layer 1: block-split interior quads / border pixels -------------
#define L1_NBI 1499   // ceil(32*222*54 / 256)
__global__ void layer1_kernel(const float* __restrict__ x)
{
    if (blockIdx.x < L1_NBI) {
        // interior quads: yy in [1,222], xq in [1,54] (xx in [4,219])
        int idx = blockIdx.x * 256 + threadIdx.x;
        if (idx >= 32 * 222 * 54) return;
        int t = idx;
        int xq = 1 + t % 54; t /= 54;
        int yy = 1 + t % 222;
        int b  = t / 222;
        int xx0 = xq * 4;

        const float* xb = x + (size_t)b * 3 * 224 * 224;
        uint32_t cb[3][3];
#pragma unroll
        for (int ic = 0; ic < 3; ++ic)
#pragma unroll
        for (int r = 0; r < 3; ++r) {
            const float4* f = (const float4*)(xb + ((size_t)ic * 224 + (yy - 1 + r)) * 224 + (xx0 - 4));
            float4 a = f[0], m = f[1], c = f[2];
            uint32_t bits =  (a.w < 0.0f ? 1u : 0u)
                          | ((m.x < 0.0f ? 1u : 0u) << 1)
                          | ((m.y < 0.0f ? 1u : 0u) << 2)
                          | ((m.z < 0.0f ? 1u : 0u) << 3)
                          | ((m.w < 0.0f ? 1u : 0u) << 4)
                          | ((c.x < 0.0f ? 1u : 0u) << 5);
            cb[ic][r] = bits;
        }
        uint32_t xm[4];
#pragma unroll
        for (int p = 0; p < 4; ++p) {
            uint32_t m = 0;
#pragma unroll
            for (int ic = 0; ic < 3; ++ic)
#pragma unroll
            for (int r = 0; r < 3; ++r)
                m |= ((cb[ic][r] >> p) & 7u) << (ic * 9 + r * 3);
            xm[p] = m;
        }
        uint32_t outw[4] = {0, 0, 0, 0};
#pragma unroll
        for (int oc = 0; oc < 32; ++oc) {
            uint32_t w = g_w1p[oc];           // uniform -> scalar
            int M = g_Mb1[4 * 32 + oc];       // interior pattern = 4
#pragma unroll
            for (int p = 0; p < 4; ++p) {
                int mm = __popc(xm[p] ^ w);
                outw[p] |= (mm < M ? 1u : 0u) << oc;
            }
        }
        uint32_t pol = g_pol1pk[4];
        uint4 o = make_uint4(outw[0] ^ pol, outw[1] ^ pol, outw[2] ^ pol, outw[3] ^ pol);
        *(uint4*)&g_h1p[((size_t)b * 224 + yy) * 224 + xx0] = o;
    } else {
        // border pixels, 1/thread: 32 * 2224 = 71168 = 278*256 exactly
        int i = (blockIdx.x - L1_NBI) * 256 + threadIdx.x;
        int b = i / 2224;
        int r = i % 2224;
        int yy, xx;
        if (r < 448) { yy = (r < 224) ? 0 : 223; xx = r % 224; }
        else { int r2 = r - 448; yy = 1 + (r2 >> 3); int k = r2 & 7; xx = (k < 4) ? k : (216 + k); }

        const float* xb = x + (size_t)b * 3 * 224 * 224;
        uint32_t xmask = 0;
#pragma unroll
        for (int ky = 0; ky < 3; ++ky) {
            int iy = yy - 1 + ky;
            if (iy < 0 || iy > 223) continue;
#pragma unroll
            for (int kx = 0; kx < 3; ++kx) {
                int ix = xx - 1 + kx;
                if (ix < 0 || ix > 223) continue;
                int sp = ky * 3 + kx;
#pragma unroll
                for (int ic = 0; ic < 3; ++ic) {
                    float v = xb[((size_t)ic * 224 + iy) * 224 + ix];
                    xmask |= (v < 0.0f ? 1u : 0u) << (ic * 9 + sp);
                }
            }
        }
        int py = (yy == 0) ? 0 : ((yy == 223) ? 2 : 1);
        int px = (xx == 0) ? 0 : ((xx == 223) ? 2 : 1);
        int pat = py * 3 + px;
        uint32_t ow = 0;
#pragma unroll
        for (int oc = 0; oc < 32; ++oc) {
            uint32_t w = g_w1p[oc];
            int mm = __popc(xmask ^ w);       // invalid bits add popc(w&inv), folded in Mb1
            int thr = g_Mb1[pat * 32 + oc];
            ow |= (mm < thr ? 1u : 0u) << oc;
        }
        ow ^= g_pol1pk[pat];
        g_h1p[((size_t)b * 224 + yy) * 224 + xx] = ow;
    }
}

// ---------- layer 2: both oc-halves per thread, block-split int/border ------
#define L2_NBI 1541   // ceil(32*111*111 / 256)
__global__ void layer2_kernel()
{
    if (blockIdx.x < L2_NBI) {
        int idx = blockIdx.x * 256 + threadIdx.x;
        if (idx >= 32 * 111 * 111) return;
        int t = idx;
        int ox = 1 + t % 111; t /= 111;
        int oy = 1 + t % 111;
        int b  = t / 111;

        const uint32_t* hb = g_h1p + (size_t)b * 224 * 224;
        uint32_t hw[9];
#pragma unroll
        for (int ky = 0; ky < 3; ++ky) {
            const uint32_t* row = hb + (2 * oy - 1 + ky) * 224 + (2 * ox - 1);
            hw[ky * 3 + 0] = row[0];
            hw[ky * 3 + 1] = row[1];
            hw[ky * 3 + 2] = row[2];
        }
        uint32_t lo = 0, hi = 0;
#pragma unroll
        for (int oc = 0; oc < 32; ++oc) {
            int mlo = 0, mhi = 0;
#pragma unroll
            for (int tt = 0; tt < 9; ++tt) {
                mlo += __popc(hw[tt] ^ g_w2p[oc * 9 + tt]);
                mhi += __popc(hw[tt] ^ g_w2p[288 + oc * 9 + tt]);
            }
            lo |= (mlo < g_Mb2[oc]      ? 1u : 0u) << oc;   // pattern 0
            hi |= (mhi < g_Mb2[32 + oc] ? 1u : 0u) << oc;
        }
        lo ^= g_pol2pk[0];
        hi ^= g_pol2pk[1];
        size_t o = ((size_t)b * 112 + oy) * 112 + ox;
        g_h2lo[o] = lo;
        g_h2hi[o] = hi;
    } else {
        int j = (blockIdx.x - L2_NBI) * 256 + threadIdx.x;
        if (j >= 32 * 223) return;
        int b = j / 223;
        int r = j % 223;
        int oy, ox;
        if (r < 112) { oy = 0; ox = r; } else { ox = 0; oy = r - 111; }

        const uint32_t* hb = g_h1p + (size_t)b * 224 * 224;
        uint32_t hw[9];
#pragma unroll
        for (int ky = 0; ky < 3; ++ky) {
            int iy = 2 * oy - 1 + ky;
#pragma unroll
            for (int kx = 0; kx < 3; ++kx) {
                int ix = 2 * ox - 1 + kx;
                bool v = (iy >= 0) && (ix >= 0);   // upper bounds always valid here
                hw[ky * 3 + kx] = v ? hb[iy * 224 + ix] : 0u;
            }
        }
        int pat = (oy == 0 ? 1 : 0) + (ox == 0 ? 2 : 0);
        const int* thrL = g_Mb2 + pat * 64;
        uint32_t lo = 0, hi = 0;
#pragma unroll
        for (int oc = 0; oc < 32; ++oc) {
            int mlo = 0, mhi = 0;
#pragma unroll
            for (int tt = 0; tt < 9; ++tt) {
                mlo += __popc(hw[tt] ^ g_w2p[oc * 9 + tt]);
                mhi += __popc(hw[tt] ^ g_w2p[288 + oc * 9 + tt]);
            }
            lo |= (mlo < thrL[oc]      ? 1u : 0u) << oc;
            hi |= (mhi < thrL[32 + oc] ? 1u : 0u) << oc;
        }
        lo ^= g_pol2pk[pat * 2 + 0];
        hi ^= g_pol2pk[pat * 2 + 1];
        size_t o = ((size_t)b * 112 + oy) * 112 + ox;
        g_h2lo[o] = lo;
        g_h2hi[o] = hi;
    }
}

// ---------- layer 3 + avgpool reduce (plain atomics) ------------------------
__global__ void layer3_kernel()
{
    int ocq = blockIdx.z;
    int b = blockIdx.y;
    int pix = blockIdx.x * blockDim.x + threadIdx.x;
    bool valid = pix < 56 * 56;
    int oy = valid ? pix / 56 : 0;
    int ox = valid ? pix % 56 : 0;

    const uint32_t* hlo = g_h2lo + (size_t)b * 112 * 112;
    const uint32_t* hhi = g_h2hi + (size_t)b * 112 * 112;
    uint64_t hw[9];
    bool tv[9];
    int nvt = 0;
#pragma unroll
    for (int ky = 0; ky < 3; ++ky) {
        int iy = 2 * oy - 1 + ky;
        bool vy = (iy >= 0 && iy < 112);
#pragma unroll
        for (int kx = 0; kx < 3; ++kx) {
            int ix = 2 * ox - 1 + kx;
            bool v = valid && vy && (ix >= 0) && (ix < 112);
            int tt = ky * 3 + kx;
            tv[tt] = v;
            nvt += v ? 1 : 0;
            hw[tt] = v ? ((uint64_t)hlo[iy * 112 + ix] | ((uint64_t)hhi[iy * 112 + ix] << 32)) : 0ull;
        }
    }
    int base = 64 * nvt;
    int lane = threadIdx.x & 63;
    unsigned long long am = __ballot(valid ? 1 : 0);
    int nact = __popcll(am);

    const uint64_t* wp = g_w3p + ocq * 288;
    const float* invp = g_inv3 + ocq * 32;
    const float* shp  = g_sh3  + ocq * 32;
#pragma unroll
    for (int oc = 0; oc < 32; ++oc) {
        int s = 0;
#pragma unroll
        for (int tt = 0; tt < 9; ++tt) {
            uint64_t w = wp[oc * 9 + tt];           // uniform -> s_load
            s += __popcll(hw[tt] ^ (tv[tt] ? w : 0ull));
        }
        int val = base - 2 * s;
        float y = __fadd_rn(__fmul_rn((float)val, invp[oc]), shp[oc]);
        int neg = (valid && y < 0.0f) ? 1 : 0;
        unsigned long long bm = __ballot(neg);
        if (lane == 0) {
            int cneg = __popcll(bm);
            atomicAdd(&g_acc[b * 128 + ocq * 32 + oc], nact - 2 * cneg);
        }
    }
}

// ---------- final: mean + fc ------------------------------------------------
__global__ void fc_kernel(
    const float* __restrict__ fc_w, const float* __restrict__ fc_b,
    float* __restrict__ out)
{
    int tid = threadIdx.x;
    if (tid >= 64) return;
    int b = tid >> 1, k = tid & 1;
    float s = fc_b[k];
    for (int oc = 0; oc < 128; ++oc) {
        float h = __fdiv_rn((float)g_acc[b * 128 + oc], 3136.0f);
        s = __fadd_rn(s, __fmul_rn(h, fc_w[k * 128 + oc]));
    }
    out[b * 2 + k] = s;
}

// ---------------------------------------------------------------------------
extern "C" void kernel_launch(void* const* d_in, const int* in_sizes, int n_in,
                              void* d_out, int out_size, void* d_ws, size_t ws_size,
                              hipStream_t stream)
{
    const float* x   = (const float*)d_in[0];
    const float* w1  = (const float*)d_in[1];
    const float* w2  = (const float*)d_in[2];
    const float* w3  = (const float*)d_in[3];
    const float* g1  = (const float*)d_in[4];
    const float* b1  = (const float*)d_in[5];
    const float* m1  = (const float*)d_in[6];
    const float* v1  = (const float*)d_in[7];
    const float* g2  = (const float*)d_in[8];
    const float* b2  = (const float*)d_in[9];
    const float* m2  = (const float*)d_in[10];
    const float* v2  = (const float*)d_in[11];
    const float* g3  = (const float*)d_in[12];
    const float* b3  = (const float*)d_in[13];
    const float* m3  = (const float*)d_in[14];
    const float* v3  = (const float*)d_in[15];
    const float* fcw = (const float*)d_in[16];
    const float* fcb = (const float*)d_in[17];
    float* out = (float*)d_out;
    (void)d_ws; (void)ws_size; (void)in_sizes; (void)n_in; (void)out_size;

    prep_kernel<<<16, 256, 0, stream>>>(w1, w2, w3,
        g1, b1, m1, v1, g2, b2, m2, v2, g3, b3, m3, v3);

    {   // layer 1: interior-quad blocks + border-pixel blocks
        layer1_kernel<<<L1_NBI + 278, 256, 0, stream>>>(x);
    }
    {   // layer 2: interior blocks + border blocks (both halves per thread)
        layer2_kernel<<<L2_NBI + 28, 256, 0, stream>>>();
    }
    {   // layer 3 + pool reduce
        dim3 grid((56 * 56 + 255) / 256, 32, 4);
        layer3_kernel<<<grid, 256, 0, stream>>>();
    }
    // fc
    fc_kernel<<<1, 64, 0, stream>>>(fcw, fcb, out);
}